// Round 1
// baseline (2403.024 us; speedup 1.0000x reference)
//
#include <hip/hip_runtime.h>

#define TSEQ 32
#define BATCH 32768
#define HID 128
#define GATES 512
#define PLEN 12

typedef __attribute__((ext_vector_type(8))) short bf16x8;
typedef __attribute__((ext_vector_type(4))) float f32x4;

__device__ __forceinline__ unsigned short f2bf(float f){
  unsigned u = __float_as_uint(f);
  u += 0x7fffu + ((u >> 16) & 1u);
  return (unsigned short)(u >> 16);
}
__device__ __forceinline__ float bf2f(unsigned short b){
  return __uint_as_float(((unsigned)b) << 16);
}
__device__ __forceinline__ float sigm(float x){ return 1.0f / (1.0f + __expf(-x)); }
__device__ __forceinline__ float tanhf_(float x){ return 1.0f - 2.0f / (__expf(2.0f * x) + 1.0f); }

// swizzled LDS address: 256 B rows (128 bf16), XOR bits 4-6 with row&7 (T2)
__device__ __forceinline__ unsigned swz(unsigned row, unsigned byteoff){
  return row * 256u + (byteoff ^ ((row & 7u) << 4));
}
__device__ __forceinline__ bf16x8 ldsfrag(const unsigned short* base, unsigned row, unsigned byteoff){
  return *(const bf16x8*)((const char*)base + swz(row, byteoff));
}
__device__ __forceinline__ f32x4 mfma16(bf16x8 a, bf16x8 b, f32x4 c){
  return __builtin_amdgcn_mfma_f32_16x16x32_bf16(a, b, c, 0, 0, 0);
}

// stage a [512][128] f32 weight matrix into swizzled bf16 LDS
__device__ __forceinline__ void stage_w(const float* __restrict__ W, unsigned short* dst, int tid){
  #pragma unroll 1
  for (int i = tid; i < GATES * (HID / 4); i += 512){
    int n  = i >> 5;
    int k4 = (i & 31) << 2;
    f32x4 v = *(const f32x4*)(W + (size_t)n * HID + k4);
    unsigned lo = (unsigned)f2bf(v[0]) | ((unsigned)f2bf(v[1]) << 16);
    unsigned hi = (unsigned)f2bf(v[2]) | ((unsigned)f2bf(v[3]) << 16);
    unsigned long long v64 = (unsigned long long)lo | ((unsigned long long)hi << 32);
    *(unsigned long long*)((char*)dst + swz((unsigned)n, (unsigned)(2 * k4))) = v64;
  }
}

__global__ __launch_bounds__(512, 2)
void mcdlstm_kernel(const float* __restrict__ g_obs,
                    const float* __restrict__ g_Wih0, const float* __restrict__ g_Whh0,
                    const float* __restrict__ g_bih0, const float* __restrict__ g_bhh0,
                    const float* __restrict__ g_Wih1, const float* __restrict__ g_Whh1,
                    const float* __restrict__ g_bih1, const float* __restrict__ g_bhh1,
                    const float* __restrict__ g_Wihc, const float* __restrict__ g_Whhc,
                    const float* __restrict__ g_bihc, const float* __restrict__ g_bhhc,
                    const float* __restrict__ g_Wout, const float* __restrict__ g_bout,
                    const float* __restrict__ g_encu, const float* __restrict__ g_hnu,
                    const float* __restrict__ g_decu,
                    float* __restrict__ g_out)
{
  __shared__ __align__(16) unsigned short s_w[GATES * HID];   // 128 KiB weight (Whh1, then Whhc)
  __shared__ __align__(16) unsigned short s_h0[32 * HID];     // 8 KiB each, swizzled bf16
  __shared__ __align__(16) unsigned short s_ys[32 * HID];
  __shared__ __align__(16) unsigned short s_h1[32 * HID];
  __shared__ unsigned s_obs[TSEQ * 32];                       // [t][r] packed bf16x2
  __shared__ float s_wout[2 * HID];
  __shared__ float s_bout[2];
  __shared__ float s_inp[32 * 2];

  const int tid  = (int)threadIdx.x;
  const int lane = tid & 63;
  const int wv   = tid >> 6;     // 0..7
  const int l15  = lane & 15;
  const int cg   = lane >> 4;    // 0..3
  const int r0   = (int)blockIdx.x * 32;
  const int uj   = wv * 16 + l15;   // hidden unit 0..127 owned by this lane

  const float DSC = (float)(1.0 / 0.7);

  // ---- stage Whh1, obs tile; zero recurrent state buffers ----
  stage_w(g_Whh1, s_w, tid);
  #pragma unroll 1
  for (int i = tid; i < 32 * TSEQ; i += 512){
    int r = i >> 5, t = i & 31;
    const float* p = g_obs + (size_t)(r0 + r) * (TSEQ * 2) + t * 2;
    s_obs[t * 32 + r] = (unsigned)f2bf(p[0]) | ((unsigned)f2bf(p[1]) << 16);
  }
  #pragma unroll 1
  for (int i = tid; i < 32 * HID; i += 512){ s_h0[i] = 0; s_h1[i] = 0; }

  // ---- per-wave register B-fragments for Whh0 and Wih1 ----
  bf16x8 wr0[4][4], wr1[4][4];   // [gate q][k-tile]
  #pragma unroll
  for (int q = 0; q < 4; ++q){
    #pragma unroll
    for (int kt = 0; kt < 4; ++kt){
      int n = q * HID + uj;
      {
        const float* p0 = g_Whh0 + (size_t)n * HID + kt * 32 + cg * 8;
        f32x4 a = *(const f32x4*)p0;
        f32x4 b = *(const f32x4*)(p0 + 4);
        bf16x8 f;
        f[0]=(short)f2bf(a[0]); f[1]=(short)f2bf(a[1]); f[2]=(short)f2bf(a[2]); f[3]=(short)f2bf(a[3]);
        f[4]=(short)f2bf(b[0]); f[5]=(short)f2bf(b[1]); f[6]=(short)f2bf(b[2]); f[7]=(short)f2bf(b[3]);
        wr0[q][kt] = f;
      }
      {
        const float* p1 = g_Wih1 + (size_t)n * HID + kt * 32 + cg * 8;
        f32x4 a = *(const f32x4*)p1;
        f32x4 b = *(const f32x4*)(p1 + 4);
        bf16x8 f;
        f[0]=(short)f2bf(a[0]); f[1]=(short)f2bf(a[1]); f[2]=(short)f2bf(a[2]); f[3]=(short)f2bf(a[3]);
        f[4]=(short)f2bf(b[0]); f[5]=(short)f2bf(b[1]); f[6]=(short)f2bf(b[2]); f[7]=(short)f2bf(b[3]);
        wr1[q][kt] = f;
      }
    }
  }
  float b0[4], b1[4], wia[4], wib[4];
  #pragma unroll
  for (int q = 0; q < 4; ++q){
    int n = q * HID + uj;
    b0[q] = g_bih0[n] + g_bhh0[n];
    b1[q] = g_bih1[n] + g_bhh1[n];
    wia[q] = g_Wih0[n * 2];
    wib[q] = g_Wih0[n * 2 + 1];
  }
  float c0[8], c1[8], h1r[8];
  #pragma unroll
  for (int p = 0; p < 8; ++p){ c0[p] = 0.f; c1[p] = 0.f; h1r[p] = 0.f; }

  __syncthreads();

  // ================= encoder: fused layer0+layer1 scan =================
  #pragma unroll 1
  for (int t = 0; t < TSEQ; ++t){
    // --- phase A: layer0 gates = b0 + x_t@Wih0^T + h0@Whh0^T ---
    float uenc[8];
    {
      const float* up = g_encu + (size_t)t * (BATCH * HID) + (size_t)r0 * HID + uj;
      #pragma unroll
      for (int m = 0; m < 2; ++m)
        #pragma unroll
        for (int e = 0; e < 4; ++e){
          int row = m * 16 + cg * 4 + e;
          uenc[m * 4 + e] = up[(size_t)row * HID];
        }
    }
    f32x4 acc[2][4];
    #pragma unroll
    for (int m = 0; m < 2; ++m){
      #pragma unroll
      for (int e = 0; e < 4; ++e){
        int row = m * 16 + cg * 4 + e;
        unsigned pk = s_obs[t * 32 + row];
        float x0 = bf2f((unsigned short)(pk & 0xffffu));
        float x1 = bf2f((unsigned short)(pk >> 16));
        #pragma unroll
        for (int q = 0; q < 4; ++q)
          acc[m][q][e] = b0[q] + wia[q] * x0 + wib[q] * x1;
      }
    }
    #pragma unroll
    for (int kt = 0; kt < 4; ++kt){
      bf16x8 a0 = ldsfrag(s_h0, (unsigned)l15,        (unsigned)(kt * 64 + cg * 16));
      bf16x8 a1 = ldsfrag(s_h0, (unsigned)(16 + l15), (unsigned)(kt * 64 + cg * 16));
      #pragma unroll
      for (int q = 0; q < 4; ++q){
        acc[0][q] = mfma16(a0, wr0[q][kt], acc[0][q]);
        acc[1][q] = mfma16(a1, wr0[q][kt], acc[1][q]);
      }
    }
    __syncthreads();
    // --- phase B: layer0 pointwise; write h0 and dropped ys0 ---
    #pragma unroll
    for (int m = 0; m < 2; ++m){
      #pragma unroll
      for (int e = 0; e < 4; ++e){
        int row = m * 16 + cg * 4 + e;
        int p = m * 4 + e;
        float gi = acc[m][0][e], gf = acc[m][1][e], gg = acc[m][2][e], go = acc[m][3][e];
        float cc = sigm(gf) * c0[p] + sigm(gi) * tanhf_(gg);
        c0[p] = cc;
        float h = sigm(go) * tanhf_(cc);
        *(unsigned short*)((char*)s_h0 + swz((unsigned)row, (unsigned)(2 * uj))) = f2bf(h);
        float ys = (uenc[p] >= 0.3f) ? h * DSC : 0.0f;
        *(unsigned short*)((char*)s_ys + swz((unsigned)row, (unsigned)(2 * uj))) = f2bf(ys);
      }
    }
    __syncthreads();
    // --- phase C: layer1 gates = b1 + ys0@Wih1^T + h1@Whh1^T ---
    #pragma unroll
    for (int m = 0; m < 2; ++m)
      #pragma unroll
      for (int q = 0; q < 4; ++q){
        f32x4 z = {b1[q], b1[q], b1[q], b1[q]};
        acc[m][q] = z;
      }
    #pragma unroll
    for (int kt = 0; kt < 4; ++kt){
      bf16x8 y0  = ldsfrag(s_ys, (unsigned)l15,        (unsigned)(kt * 64 + cg * 16));
      bf16x8 y1  = ldsfrag(s_ys, (unsigned)(16 + l15), (unsigned)(kt * 64 + cg * 16));
      bf16x8 hf0 = ldsfrag(s_h1, (unsigned)l15,        (unsigned)(kt * 64 + cg * 16));
      bf16x8 hf1 = ldsfrag(s_h1, (unsigned)(16 + l15), (unsigned)(kt * 64 + cg * 16));
      #pragma unroll
      for (int q = 0; q < 4; ++q){
        bf16x8 wb = ldsfrag(s_w, (unsigned)(q * HID + uj), (unsigned)(kt * 64 + cg * 16));
        acc[0][q] = mfma16(y0,  wr1[q][kt], acc[0][q]);
        acc[1][q] = mfma16(y1,  wr1[q][kt], acc[1][q]);
        acc[0][q] = mfma16(hf0, wb,         acc[0][q]);
        acc[1][q] = mfma16(hf1, wb,         acc[1][q]);
      }
    }
    __syncthreads();
    // --- phase D: layer1 pointwise; write h1 ---
    #pragma unroll
    for (int m = 0; m < 2; ++m){
      #pragma unroll
      for (int e = 0; e < 4; ++e){
        int row = m * 16 + cg * 4 + e;
        int p = m * 4 + e;
        float gi = acc[m][0][e], gf = acc[m][1][e], gg = acc[m][2][e], go = acc[m][3][e];
        float cc = sigm(gf) * c1[p] + sigm(gi) * tanhf_(gg);
        c1[p] = cc;
        float h = sigm(go) * tanhf_(cc);
        h1r[p] = h;
        *(unsigned short*)((char*)s_h1 + swz((unsigned)row, (unsigned)(2 * uj))) = f2bf(h);
      }
    }
    // no barrier needed: next phase A touches only s_h0/s_obs; its barrier orders h1
  }

  // ================= transition: hn dropout, swap weights =================
  {
    const float* up = g_hnu + (size_t)r0 * HID + uj;
    #pragma unroll
    for (int m = 0; m < 2; ++m)
      #pragma unroll
      for (int e = 0; e < 4; ++e){
        int row = m * 16 + cg * 4 + e;
        int p = m * 4 + e;
        float u = up[(size_t)row * HID];
        float h = (u >= 0.3f) ? h1r[p] * DSC : 0.0f;
        *(unsigned short*)((char*)s_h1 + swz((unsigned)row, (unsigned)(2 * uj))) = f2bf(h);
      }
  }
  __syncthreads();
  stage_w(g_Whhc, s_w, tid);
  if (tid < 256) s_wout[tid] = g_Wout[tid];
  if (tid < 2)   s_bout[tid] = g_bout[tid];
  if (tid < 64){
    int r = tid >> 1, o = tid & 1;
    s_inp[r * 2 + o] = g_obs[(size_t)(r0 + r) * (TSEQ * 2) + 31 * 2 + o];
  }
  float bc[4], wca[4], wcb[4];
  #pragma unroll
  for (int q = 0; q < 4; ++q){
    int n = q * HID + uj;
    bc[q]  = g_bihc[n] + g_bhhc[n];
    wca[q] = g_Wihc[n * 2];
    wcb[q] = g_Wihc[n * 2 + 1];
  }
  __syncthreads();

  // ================= decoder =================
  #pragma unroll 1
  for (int t = 0; t < PLEN; ++t){
    float ud[8];
    {
      const float* up = g_decu + (size_t)t * (BATCH * HID) + (size_t)r0 * HID + uj;
      #pragma unroll
      for (int m = 0; m < 2; ++m)
        #pragma unroll
        for (int e = 0; e < 4; ++e){
          int row = m * 16 + cg * 4 + e;
          ud[m * 4 + e] = up[(size_t)row * HID];
        }
    }
    f32x4 acc[2][4];
    #pragma unroll
    for (int m = 0; m < 2; ++m){
      #pragma unroll
      for (int e = 0; e < 4; ++e){
        int row = m * 16 + cg * 4 + e;
        float x0 = s_inp[row * 2], x1 = s_inp[row * 2 + 1];
        #pragma unroll
        for (int q = 0; q < 4; ++q)
          acc[m][q][e] = bc[q] + wca[q] * x0 + wcb[q] * x1;
      }
    }
    #pragma unroll
    for (int kt = 0; kt < 4; ++kt){
      bf16x8 a0 = ldsfrag(s_h1, (unsigned)l15,        (unsigned)(kt * 64 + cg * 16));
      bf16x8 a1 = ldsfrag(s_h1, (unsigned)(16 + l15), (unsigned)(kt * 64 + cg * 16));
      #pragma unroll
      for (int q = 0; q < 4; ++q){
        bf16x8 wb = ldsfrag(s_w, (unsigned)(q * HID + uj), (unsigned)(kt * 64 + cg * 16));
        acc[0][q] = mfma16(a0, wb, acc[0][q]);
        acc[1][q] = mfma16(a1, wb, acc[1][q]);
      }
    }
    __syncthreads();
    #pragma unroll
    for (int m = 0; m < 2; ++m){
      #pragma unroll
      for (int e = 0; e < 4; ++e){
        int row = m * 16 + cg * 4 + e;
        int p = m * 4 + e;
        float gi = acc[m][0][e], gf = acc[m][1][e], gg = acc[m][2][e], go = acc[m][3][e];
        float cc = sigm(gf) * c1[p] + sigm(gi) * tanhf_(gg);
        c1[p] = cc;
        float h = sigm(go) * tanhf_(cc);
        h = (ud[p] >= 0.3f) ? h * DSC : 0.0f;
        *(unsigned short*)((char*)s_h1 + swz((unsigned)row, (unsigned)(2 * uj))) = f2bf(h);
      }
    }
    __syncthreads();
    if (tid < 64){
      int r = tid >> 1, o = tid & 1;
      float sum = s_bout[o];
      #pragma unroll
      for (int j8 = 0; j8 < 16; ++j8){
        bf16x8 hv = *(const bf16x8*)((const char*)s_h1 + swz((unsigned)r, (unsigned)(j8 * 16)));
        #pragma unroll
        for (int e = 0; e < 8; ++e)
          sum += bf2f((unsigned short)hv[e]) * s_wout[o * HID + j8 * 8 + e];
      }
      g_out[((size_t)(r0 + r) * PLEN + t) * 2 + o] = sum;
      s_inp[r * 2 + o] = sum;
    }
    __syncthreads();
  }
}

extern "C" void kernel_launch(void* const* d_in, const int* in_sizes, int n_in,
                              void* d_out, int out_size, void* d_ws, size_t ws_size,
                              hipStream_t stream){
  const float* obs  = (const float*)d_in[0];
  const float* Wih0 = (const float*)d_in[1];
  const float* Whh0 = (const float*)d_in[2];
  const float* bih0 = (const float*)d_in[3];
  const float* bhh0 = (const float*)d_in[4];
  const float* Wih1 = (const float*)d_in[5];
  const float* Whh1 = (const float*)d_in[6];
  const float* bih1 = (const float*)d_in[7];
  const float* bhh1 = (const float*)d_in[8];
  const float* Wihc = (const float*)d_in[9];
  const float* Whhc = (const float*)d_in[10];
  const float* bihc = (const float*)d_in[11];
  const float* bhhc = (const float*)d_in[12];
  const float* Wout = (const float*)d_in[13];
  const float* boutp= (const float*)d_in[14];
  const float* encu = (const float*)d_in[15];
  const float* hnu  = (const float*)d_in[16];
  const float* decu = (const float*)d_in[17];
  (void)n_in; (void)out_size; (void)d_ws; (void)ws_size;

  dim3 grid(BATCH / 32), block(512);
  hipLaunchKernelGGL(mcdlstm_kernel, grid, block, 0, stream,
                     obs, Wih0, Whh0, bih0, bhh0, Wih1, Whh1, bih1, bhh1,
                     Wihc, Whhc, bihc, bhhc, Wout, boutp, encu, hnu, decu,
                     (float*)d_out);
}